// Round 6
// baseline (174.032 us; speedup 1.0000x reference)
//
#include <hip/hip_runtime.h>

#define B_   32
#define ICN  1152
#define OCN  10
#define IDN  8
#define ODN  16
#define NIT  5
#define EPS  1e-20f
#define OUTN (B_ * OCN * ODN)   // 5120
#define KI   6                  // ics per wave (pipelined)
#define NICW (ICN / KI)         // 192 wave-slots per bgrp
#define WPB  4                  // waves per block
#define NIC4 (NICW / WPB)       // 48 ic-chunks
#define BGRP 11                 // ceil(32 / 3 b's per wave)
#define NBLK (NIC4 * BGRP)      // 528 blocks of 256
#define NROW NIC4               // 48 ws rows

// non-rematerializable pin: value becomes an asm def -> reload is illegal
#define KEEP(x) asm volatile("" : "+v"(x))

// swap with neighbor lane (l^1) via DPP quad_perm [1,0,3,2] — VALU pipe
__device__ __forceinline__ float lane_swap1(float x) {
  int i = __builtin_bit_cast(int, x);
  int r = __builtin_amdgcn_mov_dpp(i, 0xB1, 0xF, 0xF, false);
  return __builtin_bit_cast(float, r);
}

__device__ __forceinline__ float4 f4_fma(const float4 a, const float4 b, const float4 c) {
  float4 r;
  r.x = fmaf(a.x, b.x, c.x); r.y = fmaf(a.y, b.y, c.y);
  r.z = fmaf(a.z, b.z, c.z); r.w = fmaf(a.w, b.w, c.w);
  return r;
}
__device__ __forceinline__ float4 f4_mul(const float4 a, const float4 b) {
  float4 r; r.x = a.x*b.x; r.y = a.y*b.y; r.z = a.z*b.z; r.w = a.w*b.w; return r;
}
__device__ __forceinline__ float4 f4_scale(const float4 a, const float s) {
  float4 r; r.x = a.x*s; r.y = a.y*s; r.z = a.z*s; r.w = a.w*s; return r;
}
__device__ __forceinline__ float f4_hsum(const float4 a) { return (a.x + a.y) + (a.z + a.w); }

struct WB { float4 v[16]; };   // v[2*id+p]: 8 floats of this lane's (oc,half) id-row

__device__ __forceinline__ void load_wb(const float* __restrict__ wp, WB& b) {
#pragma unroll
  for (int id = 0; id < IDN; ++id) {
    b.v[2*id]     = *(const float4*)(wp + id * ODN);
    b.v[2*id + 1] = *(const float4*)(wp + id * ODN + 4);
  }
}
__device__ __forceinline__ void pin_wb(WB& b) {
#pragma unroll
  for (int i = 0; i < 16; ++i) {
    KEEP(b.v[i].x); KEEP(b.v[i].y); KEEP(b.v[i].z); KEEP(b.v[i].w);
  }
}

// ---------------------------------------------------------------------------
// Block = 4 waves, same bgrp, 4 consecutive ic-chunks of KI=6. Each wave:
// lane = grp(3 b's) x oc(10) x od-half(2), lanes 60..63 idle. The ic loop is
// software-pipelined: weights+x for ic k+1 are issued before compute of ic k
// (double-buffered 64-VGPR weight sets, pinned). Cross-half sums via DPP.
// Epilogue: 4 waves LDS-combine, wave 0 stores one b-slice of ws[icb4].
// ---------------------------------------------------------------------------
__global__ __launch_bounds__(256, 2) void caps_main(
    const float* __restrict__ xg, const float* __restrict__ wg,
    float* __restrict__ ws, float* __restrict__ outg, int atomic_out) {
  __shared__ __align__(16) float red[WPB][64][8];

  const int wid = threadIdx.x >> 6;
  const int l = threadIdx.x & 63;
  const int bid = blockIdx.x;
  const int bgrp = bid / NIC4;        // 0..10
  const int icb4 = bid % NIC4;        // 0..47
  const int icw = icb4 * WPB + wid;   // 0..191
  const int ic0 = icw * KI;
  const int grp = l / 20;             // 0..3 (3 = idle)
  const int q = l % 20;
  const int oc = q >> 1;
  const int half = q & 1;
  const int b = bgrp * 3 + grp;
  const bool valid = (grp < 3) && (b < B_);
  const int bb = valid ? b : 0;

  float4 acc0 = make_float4(0.f, 0.f, 0.f, 0.f);
  float4 acc1 = make_float4(0.f, 0.f, 0.f, 0.f);

  const float* wbase = wg + (size_t)(ic0 * OCN + oc) * (IDN * ODN) + half * 8;
  const float* xbase = xg + ((size_t)bb * ICN + ic0) * IDN;

  // prologue: load ic0's weights + x
  WB cur;
  load_wb(wbase, cur);
  float4 xa = ((const float4*)xbase)[0];
  float4 xb = ((const float4*)xbase)[1];

#pragma unroll
  for (int k = 0; k < KI; ++k) {
    // ---- prefetch ic k+1 (issued before compute; vmcnt keeps it in flight) ----
    WB nxt; float4 nxa, nxb;
    if (k + 1 < KI) {
      load_wb(wbase + (size_t)(k + 1) * (OCN * IDN * ODN), nxt);
      const float* xp = xbase + (k + 1) * IDN;
      nxa = ((const float4*)xp)[0];
      nxb = ((const float4*)xp)[1];
    }

    pin_wb(cur);   // wait for cur only; forbid reload during compute

    // ---- xn normalize ----
    float xn[IDN] = {xa.x, xa.y, xa.z, xa.w, xb.x, xb.y, xb.z, xb.w};
    {
      float s = 0.f;
#pragma unroll
      for (int i = 0; i < IDN; ++i) s += xn[i];
      const float r = __builtin_amdgcn_rcpf(s + EPS);
#pragma unroll
      for (int i = 0; i < IDN; ++i) { xn[i] *= r; KEEP(xn[i]); }
    }

    // ---- NNMF iterations (all in-lane except DPP pair-swaps) ----
    float4 h0 = make_float4(1.f/ODN, 1.f/ODN, 1.f/ODN, 1.f/ODN);
    float4 h1 = h0;
    for (int it = 0; it < NIT; ++it) {
      float4 ha0 = make_float4(0.f, 0.f, 0.f, 0.f);
      float4 ha1 = make_float4(0.f, 0.f, 0.f, 0.f);
#pragma unroll
      for (int id = 0; id < IDN; ++id) {
        float4 d4 = f4_mul(h0, cur.v[2*id]);
        d4 = f4_fma(h1, cur.v[2*id + 1], d4);
        const float pd = f4_hsum(d4);
        const float den = pd + lane_swap1(pd);        // full 16-od sum
        const float tc = xn[id] * __builtin_amdgcn_rcpf(den + EPS);
        ha0 = f4_fma(cur.v[2*id], make_float4(tc, tc, tc, tc), ha0);
        ha1 = f4_fma(cur.v[2*id + 1], make_float4(tc, tc, tc, tc), ha1);
      }
      h0 = f4_mul(h0, ha0);
      h1 = f4_mul(h1, ha1);
      const float ps = f4_hsum(h0) + f4_hsum(h1);
      const float hs = ps + lane_swap1(ps);           // full 16-od sum
      const float r = __builtin_amdgcn_rcpf(hs + EPS);
      h0 = f4_scale(h0, r);
      h1 = f4_scale(h1, r);
    }

    // ---- alpha, normalized over oc ----
    float ap = 0.f;
#pragma unroll
    for (int id = 0; id < IDN; ++id) {
      float4 d4 = f4_mul(h0, cur.v[2*id]);
      d4 = f4_fma(h1, cur.v[2*id + 1], d4);
      ap = fmaf(f4_hsum(d4), xn[id], ap);
    }
    const float af = ap + lane_swap1(ap);
    float asum = 0.f;
    const int gbase = grp * 20;
#pragma unroll
    for (int k2 = 0; k2 < OCN; ++k2) asum += __shfl(af, gbase + 2 * k2, 64);
    const float an = af * __builtin_amdgcn_rcpf(asum + EPS);
    acc0 = f4_fma(h0, make_float4(an, an, an, an), acc0);
    acc1 = f4_fma(h1, make_float4(an, an, an, an), acc1);

    if (k + 1 < KI) { cur = nxt; xa = nxa; xb = nxb; }
  }

  // ---- combine the block's 4 waves (same b-slice, different ics) ----
  *(float4*)&red[wid][l][0] = acc0;
  *(float4*)&red[wid][l][4] = acc1;
  __syncthreads();
  if (wid == 0) {
    float4 r0 = *(float4*)&red[0][l][0];
    float4 r1 = *(float4*)&red[0][l][4];
#pragma unroll
    for (int w = 1; w < WPB; ++w) {
      const float4 a0 = *(float4*)&red[w][l][0];
      const float4 a1 = *(float4*)&red[w][l][4];
      r0.x += a0.x; r0.y += a0.y; r0.z += a0.z; r0.w += a0.w;
      r1.x += a1.x; r1.y += a1.y; r1.z += a1.z; r1.w += a1.w;
    }
    if (valid) {
      if (!atomic_out) {
        float* dst = ws + (size_t)icb4 * OUTN + (bb * OCN + oc) * ODN + half * 8;
        ((float4*)dst)[0] = r0;
        ((float4*)dst)[1] = r1;
      } else {
        float* dst = outg + (bb * OCN + oc) * ODN + half * 8;
        atomicAdd(dst + 0, r0.x); atomicAdd(dst + 1, r0.y);
        atomicAdd(dst + 2, r0.z); atomicAdd(dst + 3, r0.w);
        atomicAdd(dst + 4, r1.x); atomicAdd(dst + 5, r1.y);
        atomicAdd(dst + 6, r1.z); atomicAdd(dst + 7, r1.w);
      }
    }
  }
}

// ---------------------------------------------------------------------------
// Single-stage reduce: out[j] = sum over 48 rows (independent loads, deep MLP).
// ---------------------------------------------------------------------------
__global__ void caps_reduce(const float* __restrict__ ws, float* __restrict__ outg) {
  const int j = blockIdx.x * 256 + threadIdx.x;
  float s = 0.f;
#pragma unroll
  for (int r = 0; r < NROW; ++r) s += ws[(size_t)r * OUTN + j];
  outg[j] = s;
}

extern "C" void kernel_launch(void* const* d_in, const int* in_sizes, int n_in,
                              void* d_out, int out_size, void* d_ws, size_t ws_size,
                              hipStream_t stream) {
  const float* x = (const float*)d_in[0];
  const float* w = (const float*)d_in[1];
  float* out = (float*)d_out;
  float* ws = (float*)d_ws;

  const size_t need = (size_t)NROW * OUTN * sizeof(float);   // ~0.98 MB

  if (ws_size >= need) {
    caps_main<<<NBLK, 256, 0, stream>>>(x, w, ws, out, 0);
    caps_reduce<<<OUTN / 256, 256, 0, stream>>>(ws, out);
  } else {
    hipMemsetAsync(out, 0, OUTN * sizeof(float), stream);
    caps_main<<<NBLK, 256, 0, stream>>>(x, w, nullptr, out, 1);
  }
}

// Round 7
// 107.959 us; speedup vs baseline: 1.6120x; 1.6120x over previous
//
#include <hip/hip_runtime.h>

#define B_   32
#define ICN  1152
#define OCN  10
#define IDN  8
#define ODN  16
#define NIT  5
#define EPS  1e-20f
#define OUTN (B_ * OCN * ODN)   // 5120
#define KI   3                  // ics per wave
#define WPB  4                  // waves per block
#define ICPB (KI * WPB)         // 12 ics per block
#define NICG (ICN / ICPB)       // 96 ic-groups
#define BGRP 11                 // ceil(32 / 3 b's per wave)
#define NBLK (NICG * BGRP)      // 1056 blocks of 256
#define NROW NICG               // 96 ws rows

// non-rematerializable pin: value becomes an asm def -> reload is illegal
#define KEEP(x) asm volatile("" : "+v"(x))

// swap with neighbor lane (l^1) via DPP quad_perm [1,0,3,2] — VALU pipe
__device__ __forceinline__ float lane_swap1(float x) {
  int i = __builtin_bit_cast(int, x);
  int r = __builtin_amdgcn_mov_dpp(i, 0xB1, 0xF, 0xF, false);
  return __builtin_bit_cast(float, r);
}

__device__ __forceinline__ float2 f2_fma(const float2 a, const float2 b, const float2 c) {
  float2 r; r.x = fmaf(a.x, b.x, c.x); r.y = fmaf(a.y, b.y, c.y); return r;
}
__device__ __forceinline__ float2 f2_mul(const float2 a, const float2 b) {
  float2 r; r.x = a.x * b.x; r.y = a.y * b.y; return r;
}

// ---------------------------------------------------------------------------
// Block = 4 waves, same bgrp; wave wid handles KI=3 consecutive ics.
// Lane = grp(3 b's) x oc(10) x od-half(2); lanes 60..63 idle. Weight
// half-slice (64 floats) single-buffered in pinned VGPRs. NNMF iterations
// run UNNORMALIZED (the update h <- h .* W^T(x ./ (W h)) is scale-invariant;
// EPS=1e-20 perturbation is 1e-19 relative) — one normalization at the end,
// folded into alpha and the output scale. Cross-half sums via DPP pair-swap.
// Epilogue: 4-wave LDS combine, wave 0 stores this bgrp's disjoint b-slice
// of ws[icg]; 96-row tree reduce follows.
// ---------------------------------------------------------------------------
__global__ __launch_bounds__(256, 2) void caps_main(
    const float* __restrict__ xg, const float* __restrict__ wg,
    float* __restrict__ ws, float* __restrict__ outg, int atomic_out) {
  __shared__ __align__(16) float red[WPB][64][8];

  const int wid = threadIdx.x >> 6;
  const int l = threadIdx.x & 63;
  const int bid = blockIdx.x;
  const int bgrp = bid / NICG;        // 0..10
  const int icg = bid % NICG;         // 0..95
  const int ic0 = icg * ICPB + wid * KI;
  const int grp = l / 20;             // 0..3 (3 = idle)
  const int q = l % 20;
  const int oc = q >> 1;
  const int half = q & 1;
  const int b = bgrp * 3 + grp;
  const bool valid = (grp < 3) && (b < B_);
  const int bb = valid ? b : 0;       // clamp for loads only

  float2 acc[4];
#pragma unroll
  for (int j = 0; j < 4; ++j) acc[j] = make_float2(0.f, 0.f);

#pragma unroll 1
  for (int k = 0; k < KI; ++k) {
    const int ic = ic0 + k;

    // ---- weights w[ic][oc][0..7][half*8 .. +8) -> 32 float2, PINNED ----
    float2 w2[IDN][4];
    {
      const float* wp = wg + ((size_t)ic * OCN + oc) * (IDN * ODN) + half * 8;
#pragma unroll
      for (int id = 0; id < IDN; ++id) {
        const float4 v0 = *(const float4*)(wp + id * ODN);
        const float4 v1 = *(const float4*)(wp + id * ODN + 4);
        w2[id][0] = make_float2(v0.x, v0.y);
        w2[id][1] = make_float2(v0.z, v0.w);
        w2[id][2] = make_float2(v1.x, v1.y);
        w2[id][3] = make_float2(v1.z, v1.w);
      }
#pragma unroll
      for (int id = 0; id < IDN; ++id) {
#pragma unroll
        for (int j = 0; j < 4; ++j) { KEEP(w2[id][j].x); KEEP(w2[id][j].y); }
      }
    }

    // ---- x[b,ic,:] normalized over id ----
    float xn[IDN];
    {
      const float* xp = xg + ((size_t)bb * ICN + ic) * IDN;
      const float4 a0 = ((const float4*)xp)[0];
      const float4 a1 = ((const float4*)xp)[1];
      xn[0] = a0.x; xn[1] = a0.y; xn[2] = a0.z; xn[3] = a0.w;
      xn[4] = a1.x; xn[5] = a1.y; xn[6] = a1.z; xn[7] = a1.w;
      float s = 0.f;
#pragma unroll
      for (int i = 0; i < IDN; ++i) s += xn[i];
      const float r = __builtin_amdgcn_rcpf(s + EPS);
#pragma unroll
      for (int i = 0; i < IDN; ++i) { xn[i] *= r; KEEP(xn[i]); }
    }

    // ---- NNMF iterations, UNNORMALIZED (scale-invariant update) ----
    float2 h2[4];
#pragma unroll
    for (int j = 0; j < 4; ++j) h2[j] = make_float2(1.f, 1.f);

#pragma unroll
    for (int it = 0; it < NIT; ++it) {
      float2 hacc[4];
#pragma unroll
      for (int j = 0; j < 4; ++j) hacc[j] = make_float2(0.f, 0.f);
#pragma unroll
      for (int id = 0; id < IDN; ++id) {
        float2 d2 = f2_mul(h2[0], w2[id][0]);
        d2 = f2_fma(h2[1], w2[id][1], d2);
        d2 = f2_fma(h2[2], w2[id][2], d2);
        d2 = f2_fma(h2[3], w2[id][3], d2);
        const float pd = d2.x + d2.y;
        const float den = pd + lane_swap1(pd);          // full 16-od sum
        const float tc = xn[id] * __builtin_amdgcn_rcpf(den + EPS);
        const float2 t2 = make_float2(tc, tc);
#pragma unroll
        for (int j = 0; j < 4; ++j) hacc[j] = f2_fma(w2[id][j], t2, hacc[j]);
      }
#pragma unroll
      for (int j = 0; j < 4; ++j) h2[j] = f2_mul(h2[j], hacc[j]);
    }

    // ---- end normalization: s = sum_od h (full 16) ----
    float ps = 0.f;
#pragma unroll
    for (int j = 0; j < 4; ++j) ps += h2[j].x + h2[j].y;
    const float hs = ps + lane_swap1(ps);
    const float rinv = __builtin_amdgcn_rcpf(hs + EPS);

    // ---- alpha = sum_id dot(h_n, w[id]) * xn[id], normalized over oc ----
    float ap = 0.f;
#pragma unroll
    for (int id = 0; id < IDN; ++id) {
      float2 d2 = f2_mul(h2[0], w2[id][0]);
      d2 = f2_fma(h2[1], w2[id][1], d2);
      d2 = f2_fma(h2[2], w2[id][2], d2);
      d2 = f2_fma(h2[3], w2[id][3], d2);
      ap = fmaf(d2.x + d2.y, xn[id], ap);
    }
    const float af = (ap + lane_swap1(ap)) * rinv;      // alpha(b,ic,oc), h-scale removed
    float asum = 0.f;
    const int gbase = grp * 20;
#pragma unroll
    for (int k2 = 0; k2 < OCN; ++k2) asum += __shfl(af, gbase + 2 * k2, 64);
    // acc += h_n * an  ==  h * (rinv * an)
    const float sc = rinv * af * __builtin_amdgcn_rcpf(asum + EPS);
    const float2 sc2 = make_float2(sc, sc);
#pragma unroll
    for (int j = 0; j < 4; ++j) acc[j] = f2_fma(h2[j], sc2, acc[j]);
  }

  // ---- combine the block's 4 waves (same b-slice, different ics) ----
  float4 a0 = make_float4(acc[0].x, acc[0].y, acc[1].x, acc[1].y);
  float4 a1 = make_float4(acc[2].x, acc[2].y, acc[3].x, acc[3].y);
  *(float4*)&red[wid][l][0] = a0;
  *(float4*)&red[wid][l][4] = a1;
  __syncthreads();
  if (wid == 0) {
    float4 r0 = *(float4*)&red[0][l][0];
    float4 r1 = *(float4*)&red[0][l][4];
#pragma unroll
    for (int w = 1; w < WPB; ++w) {
      const float4 c0 = *(float4*)&red[w][l][0];
      const float4 c1 = *(float4*)&red[w][l][4];
      r0.x += c0.x; r0.y += c0.y; r0.z += c0.z; r0.w += c0.w;
      r1.x += c1.x; r1.y += c1.y; r1.z += c1.z; r1.w += c1.w;
    }
    if (valid) {
      if (!atomic_out) {
        float* dst = ws + (size_t)icg * OUTN + (bb * OCN + oc) * ODN + half * 8;
        ((float4*)dst)[0] = r0;
        ((float4*)dst)[1] = r1;
      } else {
        float* dst = outg + (bb * OCN + oc) * ODN + half * 8;
        atomicAdd(dst + 0, r0.x); atomicAdd(dst + 1, r0.y);
        atomicAdd(dst + 2, r0.z); atomicAdd(dst + 3, r0.w);
        atomicAdd(dst + 4, r1.x); atomicAdd(dst + 5, r1.y);
        atomicAdd(dst + 6, r1.z); atomicAdd(dst + 7, r1.w);
      }
    }
  }
}

// ---------------------------------------------------------------------------
// Single-stage reduce: out[j] = sum over 96 rows (independent loads, deep MLP).
// ---------------------------------------------------------------------------
__global__ void caps_reduce(const float* __restrict__ ws, float* __restrict__ outg) {
  const int j = blockIdx.x * 256 + threadIdx.x;
  float s = 0.f;
#pragma unroll
  for (int r = 0; r < NROW; ++r) s += ws[(size_t)r * OUTN + j];
  outg[j] = s;
}

extern "C" void kernel_launch(void* const* d_in, const int* in_sizes, int n_in,
                              void* d_out, int out_size, void* d_ws, size_t ws_size,
                              hipStream_t stream) {
  const float* x = (const float*)d_in[0];
  const float* w = (const float*)d_in[1];
  float* out = (float*)d_out;
  float* ws = (float*)d_ws;

  const size_t need = (size_t)NROW * OUTN * sizeof(float);   // ~1.97 MB

  if (ws_size >= need) {
    caps_main<<<NBLK, 256, 0, stream>>>(x, w, ws, out, 0);
    caps_reduce<<<OUTN / 256, 256, 0, stream>>>(ws, out);
  } else {
    hipMemsetAsync(out, 0, OUTN * sizeof(float), stream);
    caps_main<<<NBLK, 256, 0, stream>>>(x, w, nullptr, out, 1);
  }
}